// Round 10
// baseline (129.195 us; speedup 1.0000x reference)
//
#include <hip/hip_runtime.h>

#define NROWS 2048
#define KDIM  768
#define L     40
#define HN    (NROWS * L)   // 81920 floats per h matrix
#define MAGICF 0x7A3F0000u

#define BI 128
#define BJ 64
#define STRD 44

// ---------------------------------------------------------------------------
// Fused projection + pairwise kernel. 512 blocks x 512 threads, 1-D grid:
//   b -> pair tile (bx = b & 15 -> i0 = bx*128, by = b >> 4 -> j0 = by*64)
//   b -> producer of hxb/hy rows [b*4, b*4+4)
// Phase 1 (proj): wave w (0..7) computes one row: w<4 -> hxb row b*4+w from
//   x & W1[:, :768] (+b1); w>=4 -> hy row b*4+(w-4) from y & W1[:, 768:].
//   Lane l holds f4 slices {l, 64+l, 128+l} of the row (coalesced); per o:
//   3 coalesced W f4 loads + 12 FMA; 64-lane shfl_xor butterfly; lane==o
//   keeps the sum -> one coalesced 40-float row store.
// Handoff: stores -> __syncthreads (drains vmcnt) -> tid0 __threadfence ->
//   release-store flags[b]=MAGIC^b (agent scope; cross-XCD safe).
// Phase 2 (pair): 48 threads spin (relaxed agent loads + s_sleep) on the 32
//   hy producers of tile bx and 16 hxb producers of tile by, then fence ->
//   __syncthreads -> R5-verified 128x64 pair body -> pairE/pairT[b].
// All 512 blocks co-resident (LDS 34.6KB->4/CU, 8 waves->4/CU, VGPR<=128
// via __launch_bounds__(512,4) -> >=2/CU): spin cannot deadlock.
// ---------------------------------------------------------------------------
__global__ __launch_bounds__(512, 4) void k_fused(
    const float* __restrict__ x, const float* __restrict__ y,
    const float* __restrict__ W1, const float* __restrict__ b1,
    const float* __restrict__ W2, const float* __restrict__ b2p,
    float* __restrict__ hxb, float* __restrict__ hy,
    unsigned* __restrict__ flags,
    float* __restrict__ pairE, float* __restrict__ pairT)
{
    const int tid  = threadIdx.x;
    const int b    = blockIdx.x;         // 0..511
    const int wv   = tid >> 6;           // wave 0..7
    const int lane = tid & 63;

    // ---------------- Phase 1: projection (this block's 8 rows) ----------
    {
        const int which = wv >> 2;                   // 0: hxb/x, 1: hy/y
        const int row   = b * 4 + (wv & 3);
        const float* A  = which ? y : x;
        const float4* af = (const float4*)(A + (size_t)row * KDIM);
        float4 a0 = af[lane], a1 = af[64 + lane], a2 = af[128 + lane];
        const float4* wb = (const float4*)W1 + which * 192;  // W1 row = 384 f4
        float keep = 0.f;
#pragma unroll 4
        for (int o = 0; o < L; ++o) {
            const float4* wf = wb + (size_t)o * 384;
            float4 w0 = wf[lane], w1 = wf[64 + lane], w2 = wf[128 + lane];
            float s = a0.x*w0.x + a0.y*w0.y + a0.z*w0.z + a0.w*w0.w
                    + a1.x*w1.x + a1.y*w1.y + a1.z*w1.z + a1.w*w1.w
                    + a2.x*w2.x + a2.y*w2.y + a2.z*w2.z + a2.w*w2.w;
            s += __shfl_xor(s, 32);
            s += __shfl_xor(s, 16);
            s += __shfl_xor(s, 8);
            s += __shfl_xor(s, 4);
            s += __shfl_xor(s, 2);
            s += __shfl_xor(s, 1);
            if (lane == o) keep = s;                 // lane o keeps sum for o
        }
        if (lane < L) {
            float v = keep;
            if (!which) { v += b1[lane]; hxb[(size_t)row * L + lane] = v; }
            else        {                hy [(size_t)row * L + lane] = v; }
        }
    }
    __syncthreads();     // all 8 waves' stores drained (pre-barrier vmcnt(0))
    if (tid == 0) {
        __threadfence();                             // push rows to coherent point
        __hip_atomic_store(&flags[b], MAGICF ^ (unsigned)b,
                           __ATOMIC_RELEASE, __HIP_MEMORY_SCOPE_AGENT);
    }

    // ---------------- handoff: wait for this tile's producers ------------
    const int bx = b & 15, by = b >> 4;
    const int i0 = bx * BI, j0 = by * BJ;

    if (tid < 48) {
        int p = (tid < 32) ? (bx * 32 + tid) : (by * 16 + (tid - 32));
        unsigned want = MAGICF ^ (unsigned)p;
        while (__hip_atomic_load(&flags[p], __ATOMIC_RELAXED,
                                 __HIP_MEMORY_SCOPE_AGENT) != want)
            __builtin_amdgcn_s_sleep(2);
        __threadfence();                             // acquire side
    }
    __syncthreads();

    // ---------------- Phase 2: pair body (R5-verified) --------------------
    __shared__ float shy[BI * STRD];
    __shared__ float shx[BJ * STRD];
    __shared__ float sw2[STRD];
    __shared__ float red[16];

    for (int idx = tid; idx < BI * 10; idx += 512) {
        int rr = idx / 10, c = idx - rr * 10;
        float4 v = ((const float4*)(hy + (size_t)i0 * L))[idx];
        *(float4*)(shy + rr * STRD + c * 4) = v;
    }
    for (int idx = tid; idx < BJ * 10; idx += 512) {
        int rr = idx / 10, c = idx - rr * 10;
        float4 v = ((const float4*)(hxb + (size_t)j0 * L))[idx];
        *(float4*)(shx + rr * STRD + c * 4) = v;
    }
    if (tid < 10) ((float4*)sw2)[tid] = ((const float4*)W2)[tid];
    __syncthreads();

    const int tx = tid & 15, ty = tid >> 4;   // ty 0..31

    float acc[4][4];
#pragma unroll
    for (int u = 0; u < 4; ++u)
#pragma unroll
        for (int v = 0; v < 4; ++v) acc[u][v] = 0.f;

    float4 ayA[4], axA[4], wA4;
    float4 ayB[4], axB[4], wB4;

#define LOADF(AY, AX, W4, K4) do {                                          \
    W4 = *(const float4*)(sw2 + (K4) * 4);                                  \
    _Pragma("unroll") for (int u_ = 0; u_ < 4; ++u_)                        \
        AY[u_] = *(const float4*)(shy + (ty + 32 * u_) * STRD + (K4) * 4);  \
    _Pragma("unroll") for (int v_ = 0; v_ < 4; ++v_)                        \
        AX[v_] = *(const float4*)(shx + (tx + 16 * v_) * STRD + (K4) * 4);  \
} while (0)

#define FMAF(AY, AX, W4) do {                                               \
    _Pragma("unroll") for (int u_ = 0; u_ < 4; ++u_)                        \
    _Pragma("unroll") for (int v_ = 0; v_ < 4; ++v_) {                      \
        float t;                                                            \
        t = AY[u_].x + AX[v_].x; t = fmaxf(t, 0.f); acc[u_][v_] += t * W4.x;\
        t = AY[u_].y + AX[v_].y; t = fmaxf(t, 0.f); acc[u_][v_] += t * W4.y;\
        t = AY[u_].z + AX[v_].z; t = fmaxf(t, 0.f); acc[u_][v_] += t * W4.z;\
        t = AY[u_].w + AX[v_].w; t = fmaxf(t, 0.f); acc[u_][v_] += t * W4.w;\
    }                                                                       \
} while (0)

    LOADF(ayA, axA, wA4, 0);
    LOADF(ayB, axB, wB4, 1);
    FMAF(ayA, axA, wA4); LOADF(ayA, axA, wA4, 2);
    FMAF(ayB, axB, wB4); LOADF(ayB, axB, wB4, 3);
    FMAF(ayA, axA, wA4); LOADF(ayA, axA, wA4, 4);
    FMAF(ayB, axB, wB4); LOADF(ayB, axB, wB4, 5);
    FMAF(ayA, axA, wA4); LOADF(ayA, axA, wA4, 6);
    FMAF(ayB, axB, wB4); LOADF(ayB, axB, wB4, 7);
    FMAF(ayA, axA, wA4); LOADF(ayA, axA, wA4, 8);
    FMAF(ayB, axB, wB4); LOADF(ayB, axB, wB4, 9);
    FMAF(ayA, axA, wA4);
    FMAF(ayB, axB, wB4);

#undef LOADF
#undef FMAF

    const float b2v = b2p[0];
    const float c1  = b2v - 1.f;
    float sumE = 0.f, sumT = 0.f;
#pragma unroll
    for (int u = 0; u < 4; ++u)
#pragma unroll
        for (int v = 0; v < 4; ++v) {
            int gi = i0 + ty + 32 * u;
            int gj = j0 + tx + 16 * v;
            float val = acc[u][v];
            if (gi == gj) sumT += val + b2v;
            sumE += __expf(val + c1);
        }

#pragma unroll
    for (int off = 32; off > 0; off >>= 1) {
        sumE += __shfl_down(sumE, off);
        sumT += __shfl_down(sumT, off);
    }
    int wid = tid >> 6;                     // 0..7
    if ((tid & 63) == 0) { red[wid] = sumE; red[8 + wid] = sumT; }
    __syncthreads();
    if (tid == 0) {
        float e = 0.f, t = 0.f;
#pragma unroll
        for (int q = 0; q < 8; ++q) { e += red[q]; t += red[8 + q]; }
        pairE[b] = e;
        pairT[b] = t;
    }
}

// ---------------------------------------------------------------------------
// Kernel 2: reduce 512 block-partials -> lower_bound.  (verified)
// ---------------------------------------------------------------------------
__global__ __launch_bounds__(512) void k_fin(const float* __restrict__ pairE,
                                             const float* __restrict__ pairT,
                                             float* __restrict__ out) {
    __shared__ float red[16];
    const int tid = threadIdx.x;
    float e = pairE[tid];
    float t = pairT[tid];
#pragma unroll
    for (int off = 32; off > 0; off >>= 1) {
        e += __shfl_down(e, off);
        t += __shfl_down(t, off);
    }
    int wid = tid >> 6;
    if ((tid & 63) == 0) { red[wid] = e; red[8 + wid] = t; }
    __syncthreads();
    if (tid == 0) {
        float se = 0.f, st = 0.f;
#pragma unroll
        for (int q = 0; q < 8; ++q) { se += red[q]; st += red[8 + q]; }
        const float invN = 1.0f / (float)NROWS;
        out[0] = st * invN - se * invN * invN;
    }
}

extern "C" void kernel_launch(void* const* d_in, const int* in_sizes, int n_in,
                              void* d_out, int out_size, void* d_ws, size_t ws_size,
                              hipStream_t stream) {
    const float* x  = (const float*)d_in[0];
    const float* y  = (const float*)d_in[1];
    const float* W1 = (const float*)d_in[2];
    const float* b1 = (const float*)d_in[3];
    const float* W2 = (const float*)d_in[4];
    const float* b2 = (const float*)d_in[5];
    float* out = (float*)d_out;

    float* wsf      = (float*)d_ws;
    unsigned* flags = (unsigned*)wsf;        // 512 u32 (poisoned each iter;
                                             //   match vs MAGIC^b, no memset)
    float* hxb      = wsf + 512;             // 2048*40, b1 folded in
    float* hy       = hxb + HN;              // 2048*40
    float* pairE    = hy + HN;               // 512
    float* pairT    = pairE + 512;           // 512

    k_fused<<<512, 512, 0, stream>>>(x, y, W1, b1, W2, b2,
                                     hxb, hy, flags, pairE, pairT);
    k_fin<<<1, 512, 0, stream>>>(pairE, pairT, out);
}

// Round 11
// 98.411 us; speedup vs baseline: 1.3128x; 1.3128x over previous
//
#include <hip/hip_runtime.h>

#define NROWS 2048
#define KDIM  768
#define L     40
#define HN    (NROWS * L)   // 81920 floats per h matrix

#define OPB   10    // o per block (40 / 4 o-groups)
#define RPB   32    // rows per block
#define WF4   192   // float4 per staged W row (768 floats)

// ---------------------------------------------------------------------------
// Kernel 0: L3/TLB warmer. The harness's 268MB poison-fill cold-wipes L3
// every iteration; 6 structurally different proj kernels all pinned at
// ~40us (= recovery window), while their compute models say <=15us.
// This kernel eats the cold-miss storm with pure streaming reads (no
// dependent chains, max MLP): 12.85MB at ~6 TB/s ~= 3-5us. Loads kept
// live via asm (guide rule #17), no stores.
// ---------------------------------------------------------------------------
__global__ __launch_bounds__(256) void k_warm(const float* __restrict__ x,
                                              const float* __restrict__ y,
                                              const float* __restrict__ W1) {
    size_t gid    = (size_t)blockIdx.x * 256 + threadIdx.x;
    size_t stride = (size_t)gridDim.x * 256;
    const float4* xf = (const float4*)x;
    const float4* yf = (const float4*)y;
    const size_t nf4 = (size_t)NROWS * KDIM / 4;     // 393216 f4 per matrix
    float4 acc = make_float4(0.f, 0.f, 0.f, 0.f);
    for (size_t i = gid; i < nf4; i += stride) {
        float4 a = xf[i], b = yf[i];
        acc.x += a.x + b.x; acc.y += a.y + b.y;
        acc.z += a.z + b.z; acc.w += a.w + b.w;
    }
    const float4* wf = (const float4*)W1;
    for (size_t i = gid; i < (size_t)L * 2 * KDIM / 4; i += stride) {
        float4 w = wf[i];
        acc.x += w.x; acc.y += w.y; acc.z += w.z; acc.w += w.w;
    }
    asm volatile("" :: "v"(acc.x), "v"(acc.y), "v"(acc.z), "v"(acc.w));
}

// ---------------------------------------------------------------------------
// Kernel 1: projection with W TILE IN LDS (R9-verified, byte-identical).
// o-split => no K-partials => no k_red kernel. grid (64,4,2)=512 = 2/CU.
// ---------------------------------------------------------------------------
__global__ __launch_bounds__(256) void k_proj(const float* __restrict__ x,
                                              const float* __restrict__ y,
                                              const float* __restrict__ W1,
                                              const float* __restrict__ b1,
                                              float* __restrict__ hxb,
                                              float* __restrict__ hy) {
    const int og    = blockIdx.y;        // 0..3 -> o range [og*10, og*10+10)
    const int which = blockIdx.z;
    const float* __restrict__ A = which ? y : x;
    const int tid = threadIdx.x;
    const int r   = tid & 31;            // 0..31 row within block
    const int s   = tid >> 5;            // 0..7 k-segment (96 k each)
    const int row0 = blockIdx.x * RPB;
    const int o0   = og * OPB;

    __shared__ float4 wlds[OPB * WF4];   // 30 KB: [10 o][192 f4]

    const float4* W1f4 = (const float4*)W1;          // 384 f4 per W1 row
    for (int i = tid; i < OPB * WF4; i += 256) {
        int ol = i / WF4, q = i - ol * WF4;
        wlds[ol * WF4 + q] = W1f4[(size_t)(o0 + ol) * 384 + which * WF4 + q];
    }

    const float4* arow = (const float4*)(A + (size_t)(row0 + r) * KDIM) + s * 24;

    float acc[OPB];
#pragma unroll
    for (int ol = 0; ol < OPB; ++ol) acc[ol] = 0.f;

    float4 aA[8], aB[8];
#pragma unroll
    for (int j = 0; j < 8; ++j) aA[j] = arow[j];     // chunk 0 (overlaps staging)
    __syncthreads();                                  // W tile ready

#define COMPUTE(AR, C) do {                                                  \
    _Pragma("unroll") for (int ol = 0; ol < OPB; ++ol) {                     \
        const float4* wp = &wlds[ol * WF4 + s * 24 + (C) * 8];               \
        float sacc = 0.f;                                                    \
        _Pragma("unroll") for (int j = 0; j < 8; ++j) {                      \
            float4 w = wp[j];                                                \
            sacc += AR[j].x * w.x + AR[j].y * w.y                            \
                  + AR[j].z * w.z + AR[j].w * w.w;                           \
        }                                                                    \
        acc[ol] += sacc;                                                     \
    } } while (0)

#pragma unroll
    for (int j = 0; j < 8; ++j) aB[j] = arow[8 + j]; // prefetch chunk 1
    COMPUTE(aA, 0);
#pragma unroll
    for (int j = 0; j < 8; ++j) aA[j] = arow[16 + j];// prefetch chunk 2
    COMPUTE(aB, 1);
    COMPUTE(aA, 2);
#undef COMPUTE

    __syncthreads();
    float* red = (float*)wlds;                       // needs 2560 floats
#pragma unroll
    for (int ol = 0; ol < OPB; ++ol)
        red[(ol * 8 + s) * 32 + r] = acc[ol];        // bank = r -> conflict-free
    __syncthreads();

    for (int idx = tid; idx < RPB * OPB; idx += 256) {
        int rr = idx / OPB, ol = idx - rr * OPB;
        float v = 0.f;
#pragma unroll
        for (int ss = 0; ss < 8; ++ss)
            v += red[(ol * 8 + ss) * 32 + rr];
        int o = o0 + ol;
        if (!which) {
            hxb[(size_t)(row0 + rr) * L + o] = v + b1[o];
        } else {
            hy[(size_t)(row0 + rr) * L + o] = v;
        }
    }
}

// ---------------------------------------------------------------------------
// Kernel 2: pairwise sum of exp(T_ij - 1) + diagonal T0 sum.  (verified)
// ---------------------------------------------------------------------------
#define BI 128
#define BJ 64
#define STRD 44

__global__ __launch_bounds__(512, 4) void k_pair(const float* __restrict__ hxb,
                                                 const float* __restrict__ hy,
                                                 const float* __restrict__ W2,
                                                 const float* __restrict__ b2p,
                                                 float* __restrict__ pairE,
                                                 float* __restrict__ pairT) {
    __shared__ float shy[BI * STRD];
    __shared__ float shx[BJ * STRD];
    __shared__ float sw2[STRD];
    __shared__ float red[16];

    const int tid = threadIdx.x;
    const int i0 = blockIdx.x * BI;
    const int j0 = blockIdx.y * BJ;

    for (int idx = tid; idx < BI * 10; idx += 512) {
        int rr = idx / 10, c = idx - rr * 10;
        float4 v = ((const float4*)(hy + (size_t)i0 * L))[idx];
        *(float4*)(shy + rr * STRD + c * 4) = v;
    }
    for (int idx = tid; idx < BJ * 10; idx += 512) {
        int rr = idx / 10, c = idx - rr * 10;
        float4 v = ((const float4*)(hxb + (size_t)j0 * L))[idx];
        *(float4*)(shx + rr * STRD + c * 4) = v;
    }
    if (tid < 10) ((float4*)sw2)[tid] = ((const float4*)W2)[tid];
    __syncthreads();

    const int tx = tid & 15, ty = tid >> 4;   // ty 0..31

    float acc[4][4];
#pragma unroll
    for (int u = 0; u < 4; ++u)
#pragma unroll
        for (int v = 0; v < 4; ++v) acc[u][v] = 0.f;

    float4 ayA[4], axA[4], wA4;
    float4 ayB[4], axB[4], wB4;

#define LOADF(AY, AX, W4, K4) do {                                          \
    W4 = *(const float4*)(sw2 + (K4) * 4);                                  \
    _Pragma("unroll") for (int u_ = 0; u_ < 4; ++u_)                        \
        AY[u_] = *(const float4*)(shy + (ty + 32 * u_) * STRD + (K4) * 4);  \
    _Pragma("unroll") for (int v_ = 0; v_ < 4; ++v_)                        \
        AX[v_] = *(const float4*)(shx + (tx + 16 * v_) * STRD + (K4) * 4);  \
} while (0)

#define FMAF(AY, AX, W4) do {                                               \
    _Pragma("unroll") for (int u_ = 0; u_ < 4; ++u_)                        \
    _Pragma("unroll") for (int v_ = 0; v_ < 4; ++v_) {                      \
        float t;                                                            \
        t = AY[u_].x + AX[v_].x; t = fmaxf(t, 0.f); acc[u_][v_] += t * W4.x;\
        t = AY[u_].y + AX[v_].y; t = fmaxf(t, 0.f); acc[u_][v_] += t * W4.y;\
        t = AY[u_].z + AX[v_].z; t = fmaxf(t, 0.f); acc[u_][v_] += t * W4.z;\
        t = AY[u_].w + AX[v_].w; t = fmaxf(t, 0.f); acc[u_][v_] += t * W4.w;\
    }                                                                       \
} while (0)

    LOADF(ayA, axA, wA4, 0);
    LOADF(ayB, axB, wB4, 1);
    FMAF(ayA, axA, wA4); LOADF(ayA, axA, wA4, 2);
    FMAF(ayB, axB, wB4); LOADF(ayB, axB, wB4, 3);
    FMAF(ayA, axA, wA4); LOADF(ayA, axA, wA4, 4);
    FMAF(ayB, axB, wB4); LOADF(ayB, axB, wB4, 5);
    FMAF(ayA, axA, wA4); LOADF(ayA, axA, wA4, 6);
    FMAF(ayB, axB, wB4); LOADF(ayB, axB, wB4, 7);
    FMAF(ayA, axA, wA4); LOADF(ayA, axA, wA4, 8);
    FMAF(ayB, axB, wB4); LOADF(ayB, axB, wB4, 9);
    FMAF(ayA, axA, wA4);
    FMAF(ayB, axB, wB4);

#undef LOADF
#undef FMAF

    const float b2v = b2p[0];
    const float c1  = b2v - 1.f;
    float sumE = 0.f, sumT = 0.f;
#pragma unroll
    for (int u = 0; u < 4; ++u)
#pragma unroll
        for (int v = 0; v < 4; ++v) {
            int gi = i0 + ty + 32 * u;
            int gj = j0 + tx + 16 * v;
            float val = acc[u][v];
            if (gi == gj) sumT += val + b2v;
            sumE += __expf(val + c1);
        }

#pragma unroll
    for (int off = 32; off > 0; off >>= 1) {
        sumE += __shfl_down(sumE, off);
        sumT += __shfl_down(sumT, off);
    }
    int wid = tid >> 6;                     // 0..7
    if ((tid & 63) == 0) { red[wid] = sumE; red[8 + wid] = sumT; }
    __syncthreads();
    if (tid == 0) {
        float e = 0.f, t = 0.f;
#pragma unroll
        for (int q = 0; q < 8; ++q) { e += red[q]; t += red[8 + q]; }
        int bid = blockIdx.y * gridDim.x + blockIdx.x;   // 0..511
        pairE[bid] = e;
        pairT[bid] = t;
    }
}

// ---------------------------------------------------------------------------
// Kernel 3: reduce 512 block-partials -> lower_bound.  (verified)
// ---------------------------------------------------------------------------
__global__ __launch_bounds__(512) void k_fin(const float* __restrict__ pairE,
                                             const float* __restrict__ pairT,
                                             float* __restrict__ out) {
    __shared__ float red[16];
    const int tid = threadIdx.x;
    float e = pairE[tid];
    float t = pairT[tid];
#pragma unroll
    for (int off = 32; off > 0; off >>= 1) {
        e += __shfl_down(e, off);
        t += __shfl_down(t, off);
    }
    int wid = tid >> 6;
    if ((tid & 63) == 0) { red[wid] = e; red[8 + wid] = t; }
    __syncthreads();
    if (tid == 0) {
        float se = 0.f, st = 0.f;
#pragma unroll
        for (int q = 0; q < 8; ++q) { se += red[q]; st += red[8 + q]; }
        const float invN = 1.0f / (float)NROWS;
        out[0] = st * invN - se * invN * invN;
    }
}

extern "C" void kernel_launch(void* const* d_in, const int* in_sizes, int n_in,
                              void* d_out, int out_size, void* d_ws, size_t ws_size,
                              hipStream_t stream) {
    const float* x  = (const float*)d_in[0];
    const float* y  = (const float*)d_in[1];
    const float* W1 = (const float*)d_in[2];
    const float* b1 = (const float*)d_in[3];
    const float* W2 = (const float*)d_in[4];
    const float* b2 = (const float*)d_in[5];
    float* out = (float*)d_out;

    float* wsf   = (float*)d_ws;
    float* hxb   = wsf;                  // 2048*40, b1 folded in
    float* hy    = hxb + HN;             // 2048*40
    float* pairE = hy + HN;              // 512
    float* pairT = pairE + 512;          // 512

    k_warm<<<1024, 256, 0, stream>>>(x, y, W1);
    k_proj<<<dim3(NROWS / RPB, 4, 2), 256, 0, stream>>>(x, y, W1, b1, hxb, hy);
    k_pair<<<dim3(NROWS / BI, NROWS / BJ), 512, 0, stream>>>(hxb, hy, W2, b2, pairE, pairT);
    k_fin<<<1, 512, 0, stream>>>(pairE, pairT, out);
}

// Round 12
// 93.691 us; speedup vs baseline: 1.3789x; 1.0504x over previous
//
#include <hip/hip_runtime.h>

#define NROWS 2048
#define KDIM  768
#define L     40
#define HN    (NROWS * L)   // 81920 floats per h matrix

#define OPB   10    // o per block (40 / 4 o-groups)
#define RPB   16    // rows per block
#define SEGS  16    // k-segments per row
#define SF4   12    // float4 per seg (48 k)
#define SP4   13    // padded seg stride in LDS f4 (52 floats -> banks spread)

// ---------------------------------------------------------------------------
// Kernel 1 (v7): W-in-LDS broadcast AND 4 waves/SIMD -- the one untested
// combination. R7 had occupancy (4 w/SIMD) but W re-streamed via L2 (~41us);
// R9 had LDS-broadcast W but only 2 w/SIMD (~41us); R6 at 1 w/SIMD was 99us.
// Here: grid (128,4,2)=1024 blocks = 4 blocks/CU (LDS 33.3KB x4 = 133KB),
// launch_bounds(256,4) caps VGPR 128 -> 16 waves/CU = 4 waves/SIMD.
// Block 256 = 16 rows x 16 segs; per-wave LDS reads = 16 distinct addrs
// (4 row-groups broadcast), seg stride 13 f4 -> 2 lanes/bank = free.
// ---------------------------------------------------------------------------
__global__ __launch_bounds__(256, 4) void k_proj(const float* __restrict__ x,
                                                 const float* __restrict__ y,
                                                 const float* __restrict__ W1,
                                                 const float* __restrict__ b1,
                                                 float* __restrict__ hxb,
                                                 float* __restrict__ hy) {
    const int og    = blockIdx.y;        // 0..3 -> o range [og*10, og*10+10)
    const int which = blockIdx.z;
    const float* __restrict__ A = which ? y : x;
    const int tid = threadIdx.x;
    const int s   = tid & 15;            // 0..15 k-segment (48 k each)
    const int r   = tid >> 4;            // 0..15 row within block
    const int row0 = blockIdx.x * RPB;
    const int o0   = og * OPB;

    __shared__ float4 wlds[OPB * SEGS * SP4];   // 2080 f4 = 33.3 KB

    // ---- issue A loads first (independent of W staging) ----
    const float4* arow = (const float4*)(A + (size_t)(row0 + r) * KDIM) + s * SF4;
    float4 a[SF4];
#pragma unroll
    for (int j = 0; j < SF4; ++j) a[j] = arow[j];

    // ---- stage W tile (10 rows x 192 f4, padded seg layout) ----
    const float4* W1f4 = (const float4*)W1;          // 384 f4 per W1 row
    for (int i = tid; i < OPB * 192; i += 256) {
        int ol = i / 192, q = i - ol * 192;
        int ss = q / SF4, j = q - ss * SF4;
        wlds[(ol * SEGS + ss) * SP4 + j] =
            W1f4[(size_t)(o0 + ol) * 384 + which * 192 + q];
    }
    __syncthreads();

    // ---- compute: per o, 12 broadcast LDS f4 + 48 FMA ----
    float acc[OPB];
#pragma unroll
    for (int ol = 0; ol < OPB; ++ol) {
        const float4* wp = &wlds[(ol * SEGS + s) * SP4];
        float sacc = 0.f;
#pragma unroll
        for (int j = 0; j < SF4; ++j) {
            float4 w = wp[j];
            sacc += a[j].x * w.x + a[j].y * w.y
                  + a[j].z * w.z + a[j].w * w.w;
        }
        acc[ol] = sacc;
    }

    // ---- cross-seg reduce via padded LDS transpose ----
    __syncthreads();
    float* red = (float*)wlds;                  // needs 2720 floats <= 8320
#pragma unroll
    for (int ol = 0; ol < OPB; ++ol)
        red[(ol * SEGS + s) * 17 + r] = acc[ol];
    __syncthreads();

    if (tid < RPB * OPB) {                       // 160 outputs
        int rr = tid / OPB, ol = tid - rr * OPB;
        float v = 0.f;
#pragma unroll
        for (int ss = 0; ss < SEGS; ++ss)
            v += red[(ol * SEGS + ss) * 17 + rr];
        int o = o0 + ol;
        if (!which) {
            hxb[(size_t)(row0 + rr) * L + o] = v + b1[o];
        } else {
            hy[(size_t)(row0 + rr) * L + o] = v;
        }
    }
}

// ---------------------------------------------------------------------------
// Kernel 2: pairwise sum of exp(T_ij - 1) + diagonal T0 sum.  (verified)
// ---------------------------------------------------------------------------
#define BI 128
#define BJ 64
#define STRD 44

__global__ __launch_bounds__(512, 4) void k_pair(const float* __restrict__ hxb,
                                                 const float* __restrict__ hy,
                                                 const float* __restrict__ W2,
                                                 const float* __restrict__ b2p,
                                                 float* __restrict__ pairE,
                                                 float* __restrict__ pairT) {
    __shared__ float shy[BI * STRD];
    __shared__ float shx[BJ * STRD];
    __shared__ float sw2[STRD];
    __shared__ float red[16];

    const int tid = threadIdx.x;
    const int i0 = blockIdx.x * BI;
    const int j0 = blockIdx.y * BJ;

    for (int idx = tid; idx < BI * 10; idx += 512) {
        int rr = idx / 10, c = idx - rr * 10;
        float4 v = ((const float4*)(hy + (size_t)i0 * L))[idx];
        *(float4*)(shy + rr * STRD + c * 4) = v;
    }
    for (int idx = tid; idx < BJ * 10; idx += 512) {
        int rr = idx / 10, c = idx - rr * 10;
        float4 v = ((const float4*)(hxb + (size_t)j0 * L))[idx];
        *(float4*)(shx + rr * STRD + c * 4) = v;
    }
    if (tid < 10) ((float4*)sw2)[tid] = ((const float4*)W2)[tid];
    __syncthreads();

    const int tx = tid & 15, ty = tid >> 4;   // ty 0..31

    float acc[4][4];
#pragma unroll
    for (int u = 0; u < 4; ++u)
#pragma unroll
        for (int v = 0; v < 4; ++v) acc[u][v] = 0.f;

    float4 ayA[4], axA[4], wA4;
    float4 ayB[4], axB[4], wB4;

#define LOADF(AY, AX, W4, K4) do {                                          \
    W4 = *(const float4*)(sw2 + (K4) * 4);                                  \
    _Pragma("unroll") for (int u_ = 0; u_ < 4; ++u_)                        \
        AY[u_] = *(const float4*)(shy + (ty + 32 * u_) * STRD + (K4) * 4);  \
    _Pragma("unroll") for (int v_ = 0; v_ < 4; ++v_)                        \
        AX[v_] = *(const float4*)(shx + (tx + 16 * v_) * STRD + (K4) * 4);  \
} while (0)

#define FMAF(AY, AX, W4) do {                                               \
    _Pragma("unroll") for (int u_ = 0; u_ < 4; ++u_)                        \
    _Pragma("unroll") for (int v_ = 0; v_ < 4; ++v_) {                      \
        float t;                                                            \
        t = AY[u_].x + AX[v_].x; t = fmaxf(t, 0.f); acc[u_][v_] += t * W4.x;\
        t = AY[u_].y + AX[v_].y; t = fmaxf(t, 0.f); acc[u_][v_] += t * W4.y;\
        t = AY[u_].z + AX[v_].z; t = fmaxf(t, 0.f); acc[u_][v_] += t * W4.z;\
        t = AY[u_].w + AX[v_].w; t = fmaxf(t, 0.f); acc[u_][v_] += t * W4.w;\
    }                                                                       \
} while (0)

    LOADF(ayA, axA, wA4, 0);
    LOADF(ayB, axB, wB4, 1);
    FMAF(ayA, axA, wA4); LOADF(ayA, axA, wA4, 2);
    FMAF(ayB, axB, wB4); LOADF(ayB, axB, wB4, 3);
    FMAF(ayA, axA, wA4); LOADF(ayA, axA, wA4, 4);
    FMAF(ayB, axB, wB4); LOADF(ayB, axB, wB4, 5);
    FMAF(ayA, axA, wA4); LOADF(ayA, axA, wA4, 6);
    FMAF(ayB, axB, wB4); LOADF(ayB, axB, wB4, 7);
    FMAF(ayA, axA, wA4); LOADF(ayA, axA, wA4, 8);
    FMAF(ayB, axB, wB4); LOADF(ayB, axB, wB4, 9);
    FMAF(ayA, axA, wA4);
    FMAF(ayB, axB, wB4);

#undef LOADF
#undef FMAF

    const float b2v = b2p[0];
    const float c1  = b2v - 1.f;
    float sumE = 0.f, sumT = 0.f;
#pragma unroll
    for (int u = 0; u < 4; ++u)
#pragma unroll
        for (int v = 0; v < 4; ++v) {
            int gi = i0 + ty + 32 * u;
            int gj = j0 + tx + 16 * v;
            float val = acc[u][v];
            if (gi == gj) sumT += val + b2v;
            sumE += __expf(val + c1);
        }

#pragma unroll
    for (int off = 32; off > 0; off >>= 1) {
        sumE += __shfl_down(sumE, off);
        sumT += __shfl_down(sumT, off);
    }
    int wid = tid >> 6;                     // 0..7
    if ((tid & 63) == 0) { red[wid] = sumE; red[8 + wid] = sumT; }
    __syncthreads();
    if (tid == 0) {
        float e = 0.f, t = 0.f;
#pragma unroll
        for (int q = 0; q < 8; ++q) { e += red[q]; t += red[8 + q]; }
        int bid = blockIdx.y * gridDim.x + blockIdx.x;   // 0..511
        pairE[bid] = e;
        pairT[bid] = t;
    }
}

// ---------------------------------------------------------------------------
// Kernel 3: reduce 512 block-partials -> lower_bound.  (verified)
// ---------------------------------------------------------------------------
__global__ __launch_bounds__(512) void k_fin(const float* __restrict__ pairE,
                                             const float* __restrict__ pairT,
                                             float* __restrict__ out) {
    __shared__ float red[16];
    const int tid = threadIdx.x;
    float e = pairE[tid];
    float t = pairT[tid];
#pragma unroll
    for (int off = 32; off > 0; off >>= 1) {
        e += __shfl_down(e, off);
        t += __shfl_down(t, off);
    }
    int wid = tid >> 6;
    if ((tid & 63) == 0) { red[wid] = e; red[8 + wid] = t; }
    __syncthreads();
    if (tid == 0) {
        float se = 0.f, st = 0.f;
#pragma unroll
        for (int q = 0; q < 8; ++q) { se += red[q]; st += red[8 + q]; }
        const float invN = 1.0f / (float)NROWS;
        out[0] = st * invN - se * invN * invN;
    }
}

extern "C" void kernel_launch(void* const* d_in, const int* in_sizes, int n_in,
                              void* d_out, int out_size, void* d_ws, size_t ws_size,
                              hipStream_t stream) {
    const float* x  = (const float*)d_in[0];
    const float* y  = (const float*)d_in[1];
    const float* W1 = (const float*)d_in[2];
    const float* b1 = (const float*)d_in[3];
    const float* W2 = (const float*)d_in[4];
    const float* b2 = (const float*)d_in[5];
    float* out = (float*)d_out;

    float* wsf   = (float*)d_ws;
    float* hxb   = wsf;                  // 2048*40, b1 folded in
    float* hy    = hxb + HN;             // 2048*40
    float* pairE = hy + HN;              // 512
    float* pairT = pairE + 512;          // 512

    k_proj<<<dim3(NROWS / RPB, 4, 2), 256, 0, stream>>>(x, y, W1, b1, hxb, hy);
    k_pair<<<dim3(NROWS / BI, NROWS / BJ), 512, 0, stream>>>(hxb, hy, W2, b2, pairE, pairT);
    k_fin<<<1, 512, 0, stream>>>(pairE, pairT, out);
}

// Round 13
// 92.245 us; speedup vs baseline: 1.4006x; 1.0157x over previous
//
#include <hip/hip_runtime.h>

#define NROWS 2048
#define KDIM  768
#define L     40
#define HN    (NROWS * L)   // 81920 floats per h matrix

#define OPB   10    // o per block (40 / 4 o-groups)
#define RPB   16    // rows per block
#define SEGS  16    // k-segments per row
#define SF4   12    // float4 per seg (48 k)
#define SP4   13    // padded seg stride in LDS f4 (52 floats -> banks spread)

// ---------------------------------------------------------------------------
// Kernel 1 (v8): R12 body + XCD-GROUPING SWIZZLE (single-variable change).
// R11 warmer proved the machine is fast post-fill (12.85MB in ~3us); R12
// still pinned ~38us. Remaining delta vs warmer: 4x A-redundancy whose
// replicas land on DIFFERENT XCDs (128 apart in linear grid, round-robin
// XCD = bid%8) -> every XCD re-fetches A from L3/HBM at ~500cyc with
// limited miss concurrency. Here: bid = 64q+8j+c -> rb=8q+c, (og,which)=j;
// all 8 replicas of a rowblock share XCD c=rb%8 -> A fetched once/XCD,
// re-read 3x as L2 HITS. Per-XCD unique set 1.75MB << 4MB L2.
// ---------------------------------------------------------------------------
__global__ __launch_bounds__(256, 4) void k_proj(const float* __restrict__ x,
                                                 const float* __restrict__ y,
                                                 const float* __restrict__ W1,
                                                 const float* __restrict__ b1,
                                                 float* __restrict__ hxb,
                                                 float* __restrict__ hy) {
    // ---- XCD-grouping decode: replicas of one rowblock -> same XCD ----
    const int bid = blockIdx.x;          // 0..1023
    const int c   = bid & 7;             // XCD (default round-robin mapping)
    const int m   = bid >> 3;            // 0..127
    const int q   = m >> 3;              // 0..15
    const int j   = m & 7;               // replica: og*2+which
    const int rb  = q * 8 + c;           // rowblock 0..127
    const int og    = j >> 1;            // 0..3
    const int which = j & 1;

    const float* __restrict__ A = which ? y : x;
    const int tid = threadIdx.x;
    const int s   = tid & 15;            // 0..15 k-segment (48 k each)
    const int r   = tid >> 4;            // 0..15 row within block
    const int row0 = rb * RPB;
    const int o0   = og * OPB;

    __shared__ float4 wlds[OPB * SEGS * SP4];   // 2080 f4 = 33.3 KB

    // ---- issue A loads first (independent of W staging) ----
    const float4* arow = (const float4*)(A + (size_t)(row0 + r) * KDIM) + s * SF4;
    float4 a[SF4];
#pragma unroll
    for (int jj = 0; jj < SF4; ++jj) a[jj] = arow[jj];

    // ---- stage W tile (10 rows x 192 f4, padded seg layout) ----
    const float4* W1f4 = (const float4*)W1;          // 384 f4 per W1 row
    for (int i = tid; i < OPB * 192; i += 256) {
        int ol = i / 192, qq = i - ol * 192;
        int ss = qq / SF4, jj = qq - ss * SF4;
        wlds[(ol * SEGS + ss) * SP4 + jj] =
            W1f4[(size_t)(o0 + ol) * 384 + which * 192 + qq];
    }
    __syncthreads();

    // ---- compute: per o, 12 broadcast LDS f4 + 48 FMA ----
    float acc[OPB];
#pragma unroll
    for (int ol = 0; ol < OPB; ++ol) {
        const float4* wp = &wlds[(ol * SEGS + s) * SP4];
        float sacc = 0.f;
#pragma unroll
        for (int jj = 0; jj < SF4; ++jj) {
            float4 w = wp[jj];
            sacc += a[jj].x * w.x + a[jj].y * w.y
                  + a[jj].z * w.z + a[jj].w * w.w;
        }
        acc[ol] = sacc;
    }

    // ---- cross-seg reduce via padded LDS transpose ----
    __syncthreads();
    float* red = (float*)wlds;                  // needs 2720 floats <= 8320
#pragma unroll
    for (int ol = 0; ol < OPB; ++ol)
        red[(ol * SEGS + s) * 17 + r] = acc[ol];
    __syncthreads();

    if (tid < RPB * OPB) {                       // 160 outputs
        int rr = tid / OPB, ol = tid - rr * OPB;
        float v = 0.f;
#pragma unroll
        for (int ss = 0; ss < SEGS; ++ss)
            v += red[(ol * SEGS + ss) * 17 + rr];
        int o = o0 + ol;
        if (!which) {
            hxb[(size_t)(row0 + rr) * L + o] = v + b1[o];
        } else {
            hy[(size_t)(row0 + rr) * L + o] = v;
        }
    }
}

// ---------------------------------------------------------------------------
// Kernel 2: pairwise sum of exp(T_ij - 1) + diagonal T0 sum.  (verified)
// ---------------------------------------------------------------------------
#define BI 128
#define BJ 64
#define STRD 44

__global__ __launch_bounds__(512, 4) void k_pair(const float* __restrict__ hxb,
                                                 const float* __restrict__ hy,
                                                 const float* __restrict__ W2,
                                                 const float* __restrict__ b2p,
                                                 float* __restrict__ pairE,
                                                 float* __restrict__ pairT) {
    __shared__ float shy[BI * STRD];
    __shared__ float shx[BJ * STRD];
    __shared__ float sw2[STRD];
    __shared__ float red[16];

    const int tid = threadIdx.x;
    const int i0 = blockIdx.x * BI;
    const int j0 = blockIdx.y * BJ;

    for (int idx = tid; idx < BI * 10; idx += 512) {
        int rr = idx / 10, cc = idx - rr * 10;
        float4 v = ((const float4*)(hy + (size_t)i0 * L))[idx];
        *(float4*)(shy + rr * STRD + cc * 4) = v;
    }
    for (int idx = tid; idx < BJ * 10; idx += 512) {
        int rr = idx / 10, cc = idx - rr * 10;
        float4 v = ((const float4*)(hxb + (size_t)j0 * L))[idx];
        *(float4*)(shx + rr * STRD + cc * 4) = v;
    }
    if (tid < 10) ((float4*)sw2)[tid] = ((const float4*)W2)[tid];
    __syncthreads();

    const int tx = tid & 15, ty = tid >> 4;   // ty 0..31

    float acc[4][4];
#pragma unroll
    for (int u = 0; u < 4; ++u)
#pragma unroll
        for (int v = 0; v < 4; ++v) acc[u][v] = 0.f;

    float4 ayA[4], axA[4], wA4;
    float4 ayB[4], axB[4], wB4;

#define LOADF(AY, AX, W4, K4) do {                                          \
    W4 = *(const float4*)(sw2 + (K4) * 4);                                  \
    _Pragma("unroll") for (int u_ = 0; u_ < 4; ++u_)                        \
        AY[u_] = *(const float4*)(shy + (ty + 32 * u_) * STRD + (K4) * 4);  \
    _Pragma("unroll") for (int v_ = 0; v_ < 4; ++v_)                        \
        AX[v_] = *(const float4*)(shx + (tx + 16 * v_) * STRD + (K4) * 4);  \
} while (0)

#define FMAF(AY, AX, W4) do {                                               \
    _Pragma("unroll") for (int u_ = 0; u_ < 4; ++u_)                        \
    _Pragma("unroll") for (int v_ = 0; v_ < 4; ++v_) {                      \
        float t;                                                            \
        t = AY[u_].x + AX[v_].x; t = fmaxf(t, 0.f); acc[u_][v_] += t * W4.x;\
        t = AY[u_].y + AX[v_].y; t = fmaxf(t, 0.f); acc[u_][v_] += t * W4.y;\
        t = AY[u_].z + AX[v_].z; t = fmaxf(t, 0.f); acc[u_][v_] += t * W4.z;\
        t = AY[u_].w + AX[v_].w; t = fmaxf(t, 0.f); acc[u_][v_] += t * W4.w;\
    }                                                                       \
} while (0)

    LOADF(ayA, axA, wA4, 0);
    LOADF(ayB, axB, wB4, 1);
    FMAF(ayA, axA, wA4); LOADF(ayA, axA, wA4, 2);
    FMAF(ayB, axB, wB4); LOADF(ayB, axB, wB4, 3);
    FMAF(ayA, axA, wA4); LOADF(ayA, axA, wA4, 4);
    FMAF(ayB, axB, wB4); LOADF(ayB, axB, wB4, 5);
    FMAF(ayA, axA, wA4); LOADF(ayA, axA, wA4, 6);
    FMAF(ayB, axB, wB4); LOADF(ayB, axB, wB4, 7);
    FMAF(ayA, axA, wA4); LOADF(ayA, axA, wA4, 8);
    FMAF(ayB, axB, wB4); LOADF(ayB, axB, wB4, 9);
    FMAF(ayA, axA, wA4);
    FMAF(ayB, axB, wB4);

#undef LOADF
#undef FMAF

    const float b2v = b2p[0];
    const float c1  = b2v - 1.f;
    float sumE = 0.f, sumT = 0.f;
#pragma unroll
    for (int u = 0; u < 4; ++u)
#pragma unroll
        for (int v = 0; v < 4; ++v) {
            int gi = i0 + ty + 32 * u;
            int gj = j0 + tx + 16 * v;
            float val = acc[u][v];
            if (gi == gj) sumT += val + b2v;
            sumE += __expf(val + c1);
        }

#pragma unroll
    for (int off = 32; off > 0; off >>= 1) {
        sumE += __shfl_down(sumE, off);
        sumT += __shfl_down(sumT, off);
    }
    int wid = tid >> 6;                     // 0..7
    if ((tid & 63) == 0) { red[wid] = sumE; red[8 + wid] = sumT; }
    __syncthreads();
    if (tid == 0) {
        float e = 0.f, t = 0.f;
#pragma unroll
        for (int qq = 0; qq < 8; ++qq) { e += red[qq]; t += red[8 + qq]; }
        int bidp = blockIdx.y * gridDim.x + blockIdx.x;   // 0..511
        pairE[bidp] = e;
        pairT[bidp] = t;
    }
}

// ---------------------------------------------------------------------------
// Kernel 3: reduce 512 block-partials -> lower_bound.  (verified)
// ---------------------------------------------------------------------------
__global__ __launch_bounds__(512) void k_fin(const float* __restrict__ pairE,
                                             const float* __restrict__ pairT,
                                             float* __restrict__ out) {
    __shared__ float red[16];
    const int tid = threadIdx.x;
    float e = pairE[tid];
    float t = pairT[tid];
#pragma unroll
    for (int off = 32; off > 0; off >>= 1) {
        e += __shfl_down(e, off);
        t += __shfl_down(t, off);
    }
    int wid = tid >> 6;
    if ((tid & 63) == 0) { red[wid] = e; red[8 + wid] = t; }
    __syncthreads();
    if (tid == 0) {
        float se = 0.f, st = 0.f;
#pragma unroll
        for (int qq = 0; qq < 8; ++qq) { se += red[qq]; st += red[8 + qq]; }
        const float invN = 1.0f / (float)NROWS;
        out[0] = st * invN - se * invN * invN;
    }
}

extern "C" void kernel_launch(void* const* d_in, const int* in_sizes, int n_in,
                              void* d_out, int out_size, void* d_ws, size_t ws_size,
                              hipStream_t stream) {
    const float* x  = (const float*)d_in[0];
    const float* y  = (const float*)d_in[1];
    const float* W1 = (const float*)d_in[2];
    const float* b1 = (const float*)d_in[3];
    const float* W2 = (const float*)d_in[4];
    const float* b2 = (const float*)d_in[5];
    float* out = (float*)d_out;

    float* wsf   = (float*)d_ws;
    float* hxb   = wsf;                  // 2048*40, b1 folded in
    float* hy    = hxb + HN;             // 2048*40
    float* pairE = hy + HN;              // 512
    float* pairT = pairE + 512;          // 512

    k_proj<<<1024, 256, 0, stream>>>(x, y, W1, b1, hxb, hy);
    k_pair<<<dim3(NROWS / BI, NROWS / BJ), 512, 0, stream>>>(hxb, hy, W2, b2, pairE, pairT);
    k_fin<<<1, 512, 0, stream>>>(pairE, pairT, out);
}

// Round 14
// 92.042 us; speedup vs baseline: 1.4036x; 1.0022x over previous
//
#include <hip/hip_runtime.h>

#define NROWS 2048
#define KDIM  768
#define L     40
#define HN    (NROWS * L)   // 81920 floats per h matrix

#define OPB   20    // o per block (40 / 2 o-groups)  -- halves A redundancy
#define RPB   16    // rows per block
#define SEGS  32    // k-segments per row (24 k each)
#define SF4   6     // float4 per seg
#define SP4   7     // padded seg stride in LDS f4

// ---------------------------------------------------------------------------
// Kernel 1 (v9): burst-volume cut. Surviving theory after 8 variants: proj
// time tracks the co-resident launch BURST (all blocks issue full demand at
// t=0; L2-miss queues serve ~8-16 B/cyc/CU). R12/R13: A 49MB (4x og-redund)
// + W 30MB = 79MB -> ~36us. Here OPB=20: A 25MB + W 30MB = 55MB.
// 512-thr blocks (16r x 32s), 512 blocks = 2/CU, launch_bounds(512,4)
// -> 16 waves/CU = 4 waves/SIMD (kept). W tile 20x768 = 60KB staged padded;
// XCD grouping: 4 replicas (2og x 2which) of each rowblock on same XCD.
// ---------------------------------------------------------------------------
__global__ __launch_bounds__(512, 4) void k_proj(const float* __restrict__ x,
                                                 const float* __restrict__ y,
                                                 const float* __restrict__ W1,
                                                 const float* __restrict__ b1,
                                                 float* __restrict__ hxb,
                                                 float* __restrict__ hy) {
    const int bid = blockIdx.x;          // 0..511
    const int c   = bid & 7;             // XCD (round-robin mapping)
    const int m   = bid >> 3;            // 0..63
    const int j   = m & 3;               // replica: og*2+which
    const int q   = m >> 2;              // 0..15
    const int rb  = q * 8 + c;           // rowblock 0..127
    const int og    = j >> 1;            // 0..1
    const int which = j & 1;

    const float* __restrict__ A = which ? y : x;
    const int tid = threadIdx.x;
    const int s   = tid & 31;            // 0..31 k-segment (24 k each)
    const int r   = tid >> 5;            // 0..15 row within block
    const int row0 = rb * RPB;
    const int o0   = og * OPB;

    __shared__ float4 wlds[OPB * SEGS * SP4];   // 4480 f4 = 71.7 KB

    // ---- issue A loads first ----
    const float4* arow = (const float4*)(A + (size_t)(row0 + r) * KDIM) + s * SF4;
    float4 a[SF4];
#pragma unroll
    for (int jj = 0; jj < SF4; ++jj) a[jj] = arow[jj];

    // ---- stage W tile (20 rows x 192 f4, padded seg layout) ----
    const float4* W1f4 = (const float4*)W1;          // 384 f4 per W1 row
    for (int i = tid; i < OPB * 192; i += 512) {
        int ol = i / 192, qq = i - ol * 192;
        int ss = qq / SF4, jj = qq - ss * SF4;
        wlds[(ol * SEGS + ss) * SP4 + jj] =
            W1f4[(size_t)(o0 + ol) * 384 + which * 192 + qq];
    }
    __syncthreads();

    // ---- compute: per o, 6 broadcast LDS f4 + 24 FMA ----
    float acc[OPB];
#pragma unroll
    for (int ol = 0; ol < OPB; ++ol) {
        const float4* wp = &wlds[(ol * SEGS + s) * SP4];
        float sacc = 0.f;
#pragma unroll
        for (int jj = 0; jj < SF4; ++jj) {
            float4 w = wp[jj];
            sacc += a[jj].x * w.x + a[jj].y * w.y
                  + a[jj].z * w.z + a[jj].w * w.w;
        }
        acc[ol] = sacc;
    }

    // ---- cross-seg reduce via LDS: red[(ss*20+ol)*21 + rr] ----
    __syncthreads();
    float* red = (float*)wlds;                  // 32*20*21 = 13440 fl = 53.8 KB
#pragma unroll
    for (int ol = 0; ol < OPB; ++ol)
        red[(s * OPB + ol) * 21 + r] = acc[ol];
    __syncthreads();

    if (tid < RPB * OPB) {                       // 320 outputs
        int rr = tid / OPB, ol = tid - rr * OPB;
        float v = 0.f;
#pragma unroll
        for (int ss = 0; ss < SEGS; ++ss)
            v += red[(ss * OPB + ol) * 21 + rr];
        int o = o0 + ol;
        if (!which) {
            hxb[(size_t)(row0 + rr) * L + o] = v + b1[o];
        } else {
            hy[(size_t)(row0 + rr) * L + o] = v;
        }
    }
}

// ---------------------------------------------------------------------------
// Kernel 2: pairwise sum of exp(T_ij - 1) + diagonal T0 sum.  (verified)
// ---------------------------------------------------------------------------
#define BI 128
#define BJ 64
#define STRD 44

__global__ __launch_bounds__(512, 4) void k_pair(const float* __restrict__ hxb,
                                                 const float* __restrict__ hy,
                                                 const float* __restrict__ W2,
                                                 const float* __restrict__ b2p,
                                                 float* __restrict__ pairE,
                                                 float* __restrict__ pairT) {
    __shared__ float shy[BI * STRD];
    __shared__ float shx[BJ * STRD];
    __shared__ float sw2[STRD];
    __shared__ float red[16];

    const int tid = threadIdx.x;
    const int i0 = blockIdx.x * BI;
    const int j0 = blockIdx.y * BJ;

    for (int idx = tid; idx < BI * 10; idx += 512) {
        int rr = idx / 10, cc = idx - rr * 10;
        float4 v = ((const float4*)(hy + (size_t)i0 * L))[idx];
        *(float4*)(shy + rr * STRD + cc * 4) = v;
    }
    for (int idx = tid; idx < BJ * 10; idx += 512) {
        int rr = idx / 10, cc = idx - rr * 10;
        float4 v = ((const float4*)(hxb + (size_t)j0 * L))[idx];
        *(float4*)(shx + rr * STRD + cc * 4) = v;
    }
    if (tid < 10) ((float4*)sw2)[tid] = ((const float4*)W2)[tid];
    __syncthreads();

    const int tx = tid & 15, ty = tid >> 4;   // ty 0..31

    float acc[4][4];
#pragma unroll
    for (int u = 0; u < 4; ++u)
#pragma unroll
        for (int v = 0; v < 4; ++v) acc[u][v] = 0.f;

    float4 ayA[4], axA[4], wA4;
    float4 ayB[4], axB[4], wB4;

#define LOADF(AY, AX, W4, K4) do {                                          \
    W4 = *(const float4*)(sw2 + (K4) * 4);                                  \
    _Pragma("unroll") for (int u_ = 0; u_ < 4; ++u_)                        \
        AY[u_] = *(const float4*)(shy + (ty + 32 * u_) * STRD + (K4) * 4);  \
    _Pragma("unroll") for (int v_ = 0; v_ < 4; ++v_)                        \
        AX[v_] = *(const float4*)(shx + (tx + 16 * v_) * STRD + (K4) * 4);  \
} while (0)

#define FMAF(AY, AX, W4) do {                                               \
    _Pragma("unroll") for (int u_ = 0; u_ < 4; ++u_)                        \
    _Pragma("unroll") for (int v_ = 0; v_ < 4; ++v_) {                      \
        float t;                                                            \
        t = AY[u_].x + AX[v_].x; t = fmaxf(t, 0.f); acc[u_][v_] += t * W4.x;\
        t = AY[u_].y + AX[v_].y; t = fmaxf(t, 0.f); acc[u_][v_] += t * W4.y;\
        t = AY[u_].z + AX[v_].z; t = fmaxf(t, 0.f); acc[u_][v_] += t * W4.z;\
        t = AY[u_].w + AX[v_].w; t = fmaxf(t, 0.f); acc[u_][v_] += t * W4.w;\
    }                                                                       \
} while (0)

    LOADF(ayA, axA, wA4, 0);
    LOADF(ayB, axB, wB4, 1);
    FMAF(ayA, axA, wA4); LOADF(ayA, axA, wA4, 2);
    FMAF(ayB, axB, wB4); LOADF(ayB, axB, wB4, 3);
    FMAF(ayA, axA, wA4); LOADF(ayA, axA, wA4, 4);
    FMAF(ayB, axB, wB4); LOADF(ayB, axB, wB4, 5);
    FMAF(ayA, axA, wA4); LOADF(ayA, axA, wA4, 6);
    FMAF(ayB, axB, wB4); LOADF(ayB, axB, wB4, 7);
    FMAF(ayA, axA, wA4); LOADF(ayA, axA, wA4, 8);
    FMAF(ayB, axB, wB4); LOADF(ayB, axB, wB4, 9);
    FMAF(ayA, axA, wA4);
    FMAF(ayB, axB, wB4);

#undef LOADF
#undef FMAF

    const float b2v = b2p[0];
    const float c1  = b2v - 1.f;
    float sumE = 0.f, sumT = 0.f;
#pragma unroll
    for (int u = 0; u < 4; ++u)
#pragma unroll
        for (int v = 0; v < 4; ++v) {
            int gi = i0 + ty + 32 * u;
            int gj = j0 + tx + 16 * v;
            float val = acc[u][v];
            if (gi == gj) sumT += val + b2v;
            sumE += __expf(val + c1);
        }

#pragma unroll
    for (int off = 32; off > 0; off >>= 1) {
        sumE += __shfl_down(sumE, off);
        sumT += __shfl_down(sumT, off);
    }
    int wid = tid >> 6;                     // 0..7
    if ((tid & 63) == 0) { red[wid] = sumE; red[8 + wid] = sumT; }
    __syncthreads();
    if (tid == 0) {
        float e = 0.f, t = 0.f;
#pragma unroll
        for (int qq = 0; qq < 8; ++qq) { e += red[qq]; t += red[8 + qq]; }
        int bidp = blockIdx.y * gridDim.x + blockIdx.x;   // 0..511
        pairE[bidp] = e;
        pairT[bidp] = t;
    }
}

// ---------------------------------------------------------------------------
// Kernel 3: reduce 512 block-partials -> lower_bound.  (verified)
// ---------------------------------------------------------------------------
__global__ __launch_bounds__(512) void k_fin(const float* __restrict__ pairE,
                                             const float* __restrict__ pairT,
                                             float* __restrict__ out) {
    __shared__ float red[16];
    const int tid = threadIdx.x;
    float e = pairE[tid];
    float t = pairT[tid];
#pragma unroll
    for (int off = 32; off > 0; off >>= 1) {
        e += __shfl_down(e, off);
        t += __shfl_down(t, off);
    }
    int wid = tid >> 6;
    if ((tid & 63) == 0) { red[wid] = e; red[8 + wid] = t; }
    __syncthreads();
    if (tid == 0) {
        float se = 0.f, st = 0.f;
#pragma unroll
        for (int qq = 0; qq < 8; ++qq) { se += red[qq]; st += red[8 + qq]; }
        const float invN = 1.0f / (float)NROWS;
        out[0] = st * invN - se * invN * invN;
    }
}

extern "C" void kernel_launch(void* const* d_in, const int* in_sizes, int n_in,
                              void* d_out, int out_size, void* d_ws, size_t ws_size,
                              hipStream_t stream) {
    const float* x  = (const float*)d_in[0];
    const float* y  = (const float*)d_in[1];
    const float* W1 = (const float*)d_in[2];
    const float* b1 = (const float*)d_in[3];
    const float* W2 = (const float*)d_in[4];
    const float* b2 = (const float*)d_in[5];
    float* out = (float*)d_out;

    float* wsf   = (float*)d_ws;
    float* hxb   = wsf;                  // 2048*40, b1 folded in
    float* hy    = hxb + HN;             // 2048*40
    float* pairE = hy + HN;              // 512
    float* pairT = pairE + 512;          // 512

    k_proj<<<512, 512, 0, stream>>>(x, y, W1, b1, hxb, hy);
    k_pair<<<dim3(NROWS / BI, NROWS / BJ), 512, 0, stream>>>(hxb, hy, W2, b2, pairE, pairT);
    k_fin<<<1, 512, 0, stream>>>(pairE, pairT, out);
}